// Round 1
// 902.391 us; speedup vs baseline: 1.0132x; 1.0132x over previous
//
#include <hip/hip_runtime.h>
#include <stdint.h>

// Problem: B=16384, N_AGENTS=32, EMBED=32, HID=64, N_ACT=5, S_DIM=512, O_DIM=256
#define BTOT   16384
#define ROWS_A 524288          // B*N_AGENTS

// workspace layout (bytes)
#define WT_OFF    0            // bf16 [1152][512]  (1120 real cols + 32 zero pad)
#define FC1T_OFF  1179648      // bf16 [64][256]
#define BQ_OFF    1212416      // f32  [524288] best_qs
// total required ws: 3,309,568 B

typedef __attribute__((ext_vector_type(8))) short bf8_t;   // 8 x bf16 (4 VGPRs)
typedef __attribute__((ext_vector_type(4))) float f4_t;    // MFMA acc

__device__ __forceinline__ f4_t mfma16(bf8_t a, bf8_t b, f4_t c) {
    return __builtin_amdgcn_mfma_f32_16x16x32_bf16(a, b, c, 0, 0, 0);
}
__device__ __forceinline__ unsigned short f2bf(float f) {   // RNE to bf16
    union { float f; uint32_t u; } x; x.f = f;
    uint32_t r = x.u + 0x7FFFu + ((x.u >> 16) & 1u);
    return (unsigned short)(r >> 16);
}
__device__ __forceinline__ bf8_t cvt8(float4 a, float4 b) { // 8 fp32 -> bf8 frag
    union { unsigned short s[8]; bf8_t v; } u;
    u.s[0] = f2bf(a.x); u.s[1] = f2bf(a.y); u.s[2] = f2bf(a.z); u.s[3] = f2bf(a.w);
    u.s[4] = f2bf(b.x); u.s[5] = f2bf(b.y); u.s[6] = f2bf(b.z); u.s[7] = f2bf(b.w);
    return u.v;
}

// async global->LDS, 16 B per lane; LDS dest is wave-uniform base + lane*16
typedef const __attribute__((address_space(1))) uint32_t* gas_ptr;
typedef __attribute__((address_space(3))) uint32_t* las_ptr;
__device__ __forceinline__ void gl_lds16(const void* g, void* l) {
    __builtin_amdgcn_global_load_lds((gas_ptr)g, (las_ptr)l, 16, 0, 0);
}

// ---------------------------------------------------------------- prep ------
// Transpose+convert weights to bf16 n-major [col][k]; Wt zero-padded to 1152
// cols so the mixer's group loop is uniform (compile-time NT=4, full unroll).
__global__ void prep_kernel(const float* __restrict__ fc1_w,   // [256][64]
                            const float* __restrict__ hw1_w,   // [512][1024]
                            const float* __restrict__ hb1_w,   // [512][32]
                            const float* __restrict__ hwf_w,   // [512][32]
                            const float* __restrict__ v1_w,    // [512][32]
                            unsigned short* __restrict__ Wt,   // [1152][512]
                            unsigned short* __restrict__ fc1t) // [64][256]
{
    int tid = blockIdx.x * 256 + threadIdx.x;
    if (tid < 73728) {                       // 1152*512/8
        int c = tid >> 6;                    // Wt row (hypernet col)
        int k0 = (tid & 63) * 8;             // k offset
        union { unsigned short s[8]; uint4 v; } pk;
        if (c < 1120) {
            const float* src; int N, sc;
            if (c < 1024)      { src = hw1_w; N = 1024; sc = c; }
            else if (c < 1056) { src = hb1_w; N = 32;   sc = c - 1024; }
            else if (c < 1088) { src = hwf_w; N = 32;   sc = c - 1056; }
            else               { src = v1_w;  N = 32;   sc = c - 1088; }
            #pragma unroll
            for (int j = 0; j < 8; ++j) pk.s[j] = f2bf(src[(size_t)(k0 + j) * N + sc]);
        } else {
            pk.v = (uint4){0u, 0u, 0u, 0u};  // zero pad cols 1120..1151
        }
        *(uint4*)(Wt + (size_t)c * 512 + k0) = pk.v;
    } else if (tid < 75776) {                // fc1t: 64*256/8 = 2048 threads
        int e = (tid - 73728) * 8;
        int n = e >> 8, k0 = e & 255;
        union { unsigned short s[8]; uint4 v; } pk;
        #pragma unroll
        for (int j = 0; j < 8; ++j) pk.s[j] = f2bf(fc1_w[(size_t)(k0 + j) * 64 + n]);
        *(uint4*)(fc1t + n * 256 + k0) = pk.v;
    }
}

// ---------------------------------------------------------- agent net -------
// A direct global->register (A-frag k-values are 8 contiguous floats), B (fc1t)
// LDS-resident; one sync per block total; epilogue fully in registers via
// 16-lane butterfly. Wave = 16 rows; 4 tiles/wave; block = 64 rows x 4 tiles.
// UNCHANGED this round: per-wave 16 KB of loads in flight, 16 waves/CU -> the
// kernel sits at the HBM roofline (537 MB stream); VALU/MFMA fully hidden.
#define A_SB 264   // fc1t LDS row stride (256+8 shorts -> 4-bank row shift)
__global__ __launch_bounds__(256, 4)
void agent_kernel(const float* __restrict__ obs,              // [524288][256]
                  const unsigned short* __restrict__ fc1t,    // [64][256] bf16
                  const float* __restrict__ fc1_b,            // [64]
                  const float* __restrict__ fc2_w,            // [64][5]
                  const float* __restrict__ fc2_b,            // [5]
                  float* __restrict__ out_q,                  // [524288][5]
                  float* __restrict__ bq)                     // [524288]
{
    __shared__ unsigned short sB[64 * A_SB];    // 33,792 B
    const int t = threadIdx.x;
    const int w = t >> 6, lane = t & 63;
    const int c0 = lane & 15, quad = lane >> 4;

    // stage fc1t (64x256 bf16) once
    {
        const uint4* src = (const uint4*)fc1t;   // 2048 uint4
        #pragma unroll
        for (int i = 0; i < 8; ++i) {
            int id = t + i * 256;
            int n = id >> 5, off = (id & 31) * 8;
            *(uint4*)(sB + n * A_SB + off) = src[id];
        }
    }
    // per-lane constants (L1-cached broadcasts)
    float b1c[4], w2l[4][5], b2[5];
    #pragma unroll
    for (int nt = 0; nt < 4; ++nt) {
        int h = nt * 16 + c0;
        b1c[nt] = fc1_b[h];
        #pragma unroll
        for (int j = 0; j < 5; ++j) w2l[nt][j] = fc2_w[h * 5 + j];
    }
    #pragma unroll
    for (int j = 0; j < 5; ++j) b2[j] = fc2_b[j];
    __syncthreads();                             // sB ready; no more barriers

    #pragma unroll 1
    for (int it = 0; it < 4; ++it) {
        size_t rbase = (size_t)blockIdx.x * 256 + it * 64 + w * 16;
        const float* arow = obs + (rbase + c0) * 256;

        f4_t acc[4];
        #pragma unroll
        for (int nt = 0; nt < 4; ++nt) acc[nt] = (f4_t){0.f, 0.f, 0.f, 0.f};

        #pragma unroll
        for (int ks = 0; ks < 8; ++ks) {         // K=256, 32/MFMA
            int kk = ks * 32 + quad * 8;
            float4 a0 = *(const float4*)(arow + kk);
            float4 a1 = *(const float4*)(arow + kk + 4);
            bf8_t af = cvt8(a0, a1);
            #pragma unroll
            for (int nt = 0; nt < 4; ++nt) {
                bf8_t bfr = *(const bf8_t*)(sB + (nt * 16 + c0) * A_SB + kk);
                acc[nt] = mfma16(af, bfr, acc[nt]);
            }
        }
        // relu + fc2 partials: lane holds hid cols {c0,16+c0,32+c0,48+c0} for
        // rows quad*4+r (C/D: col=lane&15, row=quad*4+reg)
        float p[4][5];
        #pragma unroll
        for (int r = 0; r < 4; ++r)
            #pragma unroll
            for (int j = 0; j < 5; ++j) p[r][j] = 0.f;
        #pragma unroll
        for (int nt = 0; nt < 4; ++nt)
            #pragma unroll
            for (int r = 0; r < 4; ++r) {
                float x = fmaxf(acc[nt][r] + b1c[nt], 0.f);
                #pragma unroll
                for (int j = 0; j < 5; ++j) p[r][j] += x * w2l[nt][j];
            }
        // butterfly over the 16 c0-lanes of this quad
        #pragma unroll
        for (int off = 1; off < 16; off <<= 1)
            #pragma unroll
            for (int r = 0; r < 4; ++r)
                #pragma unroll
                for (int j = 0; j < 5; ++j) p[r][j] += __shfl_xor(p[r][j], off);
        // lane c0 (<4) finishes row quad*4+c0
        float q[5];
        #pragma unroll
        for (int j = 0; j < 5; ++j) {
            float v = p[3][j];
            v = (c0 == 2) ? p[2][j] : v;
            v = (c0 == 1) ? p[1][j] : v;
            v = (c0 == 0) ? p[0][j] : v;
            q[j] = v + b2[j];
        }
        float m = q[0];
        #pragma unroll
        for (int j = 1; j < 5; ++j) m = fmaxf(m, q[j]);
        float e[5], s = 0.f;
        #pragma unroll
        for (int j = 0; j < 5; ++j) { e[j] = __expf(q[j] - m); s += e[j]; }
        float inv = 1.f / s;
        if (c0 < 4) {
            size_t G = rbase + quad * 4 + c0;
            #pragma unroll
            for (int j = 0; j < 5; ++j) out_q[G * 5 + j] = e[j] * inv;
            bq[G] = inv;                         // max prob = exp(0)/s = 1/s
        }
    }
}

// ------------------------------------------------------- hypernet + mix -----
// v2: double-buffered Wt group staging via global_load_lds (16 B), one barrier
// per group (T3 minimum 2-phase). LDS rows are LINEAR 1024 B (gload_lds needs a
// contiguous dest); bank conflicts broken by XOR swizzle byte^=((row&7)<<4),
// applied on the pre-swizzled GLOBAL source at stage time and on the ds_read
// address (both-sides-or-neither, rule #21). 16 c0-lanes -> 8 distinct 16-B
// granules -> uniform 32-bank coverage (same as old pad-520 layout).
// LDS: 2 x 64 KiB Wt buffers + 9 KiB bqs = 140,288 B -> 1 block/CU (as before;
// grid==256 means 1 block/CU regardless).
#define MX_BUF   65536
#define MX_BQOFF 131072
#define MX_SMEM  140288
__global__ __launch_bounds__(256, 2)
void mixer_kernel(const float* __restrict__ states,           // [16384][512]
                  const unsigned short* __restrict__ Wt,      // [1152][512] bf16
                  const float* __restrict__ hw1_b,            // [1024]
                  const float* __restrict__ hb1_b,            // [32]
                  const float* __restrict__ hwf_b,            // [32]
                  const float* __restrict__ v1_b,             // [32]
                  const float* __restrict__ v2_w,             // [32]
                  const float* __restrict__ v2_b,             // [1]
                  const float* __restrict__ bq,               // [16384][32]
                  float* __restrict__ qtot)                   // [16384]
{
    extern __shared__ __align__(16) char smem[];
    float* bqs = (float*)(smem + MX_BQOFF);                   // [64][36]
    const int t = threadIdx.x;
    const int B0 = blockIdx.x * 64;
    const int w = t >> 6, lane = t & 63;
    const int c0 = lane & 15, quad = lane >> 4;
    const char* WtB = (const char*)Wt;

    // stage best_qs tile (64x32), stride 36 to break bank conflicts
    #pragma unroll
    for (int i = 0; i < 2; ++i) {
        int id = t + i * 256;                   // 512 float4
        int row = id >> 3, off = (id & 7) * 4;
        *(float4*)(bqs + row * 36 + off) = *(const float4*)(bq + (size_t)(B0 + row) * 32 + off);
    }
    // A: this lane's states row -> 16 bf16 fragments (64 VGPRs), read once
    const float* srow = states + (size_t)(B0 + w * 16 + c0) * 512;
    bf8_t areg[16];
    #pragma unroll
    for (int ks = 0; ks < 16; ++ks) {
        int kk = ks * 32 + quad * 8;
        float4 a0 = *(const float4*)(srow + kk);
        float4 a1 = *(const float4*)(srow + kk + 4);
        areg[ks] = cvt8(a0, a1);
    }

    // prologue: stage group 0 into buf0 (wave w stages rows w*16..w*16+15;
    // per-lane pre-swizzled global source, linear LDS dest)
    {
        char* buf = smem;
        #pragma unroll
        for (int j = 0; j < 16; ++j) {
            int n = w * 16 + j;
            const char* src = WtB + (size_t)n * 1024 + ((lane * 16) ^ ((n & 7) << 4));
            gl_lds16(src, buf + n * 1024);
        }
    }
    asm volatile("s_waitcnt vmcnt(0)" ::: "memory");
    __syncthreads();                             // buf0 + bqs + (own areg) ready

    float y_acc[4][2] = {{0.f,0.f},{0.f,0.f},{0.f,0.f},{0.f,0.f}};
    float b1v[4][2], wfv[4][2], vhv[4][2];
    const int swz = (c0 & 7) << 4;               // row&7 == c0&7 for all nt

    #pragma unroll 1
    for (int g = 0; g < 18; ++g) {               // 16 agent groups + hb1/hwf + v1(+pad)
        char* cur = smem + ((g & 1) ? MX_BUF : 0);
        // issue next group's stage first; its latency hides under compute(g)
        if (g < 17) {
            char* nxt = smem + ((g & 1) ? 0 : MX_BUF);
            const char* gbase = WtB + (size_t)(g + 1) * 64 * 1024;
            #pragma unroll
            for (int j = 0; j < 16; ++j) {
                int n = w * 16 + j;
                const char* src = gbase + (size_t)n * 1024 + ((lane * 16) ^ ((n & 7) << 4));
                gl_lds16(src, nxt + n * 1024);
            }
        }
        f4_t acc[4];
        #pragma unroll
        for (int nt = 0; nt < 4; ++nt) acc[nt] = (f4_t){0.f, 0.f, 0.f, 0.f};
        #pragma unroll
        for (int ks = 0; ks < 16; ++ks) {
            int cb = (ks * 64 + quad * 16) ^ swz;
            #pragma unroll
            for (int nt = 0; nt < 4; ++nt) {
                bf8_t bfr = *(const bf8_t*)(cur + (nt * 16 + c0) * 1024 + cb);
                acc[nt] = mfma16(areg[ks], bfr, acc[nt]);
            }
        }
        if (g < 16) {                            // w1 cols: agent=col>>5, e=col&31
            #pragma unroll
            for (int nt = 0; nt < 4; ++nt) {
                int colg = g * 64 + nt * 16 + c0;
                int agent = colg >> 5;
                int eh = nt & 1;                 // e = eh*16 + c0
                float bias = hw1_b[colg];
                #pragma unroll
                for (int r = 0; r < 4; ++r) {
                    int rowl = w * 16 + quad * 4 + r;
                    float w1v = fabsf(acc[nt][r] + bias);
                    y_acc[r][eh] += bqs[rowl * 36 + agent] * w1v;
                }
            }
        } else if (g == 16) {                    // nt 0,1: b1; nt 2,3: wf
            #pragma unroll
            for (int nt = 0; nt < 2; ++nt) {
                float bias = hb1_b[nt * 16 + c0];
                #pragma unroll
                for (int r = 0; r < 4; ++r) b1v[r][nt] = acc[nt][r] + bias;
            }
            #pragma unroll
            for (int nt = 2; nt < 4; ++nt) {
                float bias = hwf_b[(nt - 2) * 16 + c0];
                #pragma unroll
                for (int r = 0; r < 4; ++r) wfv[r][nt - 2] = fabsf(acc[nt][r] + bias);
            }
        } else {                                 // v1 head (nt 0,1); nt 2,3 = zero pad
            #pragma unroll
            for (int nt = 0; nt < 2; ++nt) {
                float bias = v1_b[nt * 16 + c0];
                #pragma unroll
                for (int r = 0; r < 4; ++r) vhv[r][nt] = fmaxf(acc[nt][r] + bias, 0.f);
            }
        }
        // single barrier per group: drains this wave's stage loads (next buf
        // ready) and fences all waves' reads of cur before it is re-staged
        asm volatile("s_waitcnt vmcnt(0)" ::: "memory");
        __syncthreads();
    }
    // final per-row math + 16-lane reduction over e
    float v2w0 = v2_w[c0], v2w1 = v2_w[16 + c0], v2b = v2_b[0];
    float p[4];
    #pragma unroll
    for (int r = 0; r < 4; ++r) {
        float y0 = fmaxf(y_acc[r][0] + b1v[r][0], 0.f);
        float y1 = fmaxf(y_acc[r][1] + b1v[r][1], 0.f);
        p[r] = y0 * wfv[r][0] + y1 * wfv[r][1] + vhv[r][0] * v2w0 + vhv[r][1] * v2w1;
    }
    #pragma unroll
    for (int off = 1; off < 16; off <<= 1)
        #pragma unroll
        for (int r = 0; r < 4; ++r) p[r] += __shfl_xor(p[r], off);
    if (c0 == 0) {
        #pragma unroll
        for (int r = 0; r < 4; ++r)
            qtot[B0 + w * 16 + quad * 4 + r] = p[r] + v2b;
    }
}

// ---------------------------------------------------------------- launch ----
extern "C" void kernel_launch(void* const* d_in, const int* in_sizes, int n_in,
                              void* d_out, int out_size, void* d_ws, size_t ws_size,
                              hipStream_t stream) {
    const float* states = (const float*)d_in[0];
    const float* obs    = (const float*)d_in[1];
    const float* fc1_w  = (const float*)d_in[2];
    const float* fc1_b  = (const float*)d_in[3];
    const float* fc2_w  = (const float*)d_in[4];
    const float* fc2_b  = (const float*)d_in[5];
    const float* hw1_b  = (const float*)d_in[7];
    const float* hb1_w  = (const float*)d_in[8];
    const float* hb1_b  = (const float*)d_in[9];
    const float* hwf_w  = (const float*)d_in[10];
    const float* hwf_b  = (const float*)d_in[11];
    const float* v1_w   = (const float*)d_in[12];
    const float* v1_b   = (const float*)d_in[13];
    const float* v2_w   = (const float*)d_in[14];
    const float* v2_b   = (const float*)d_in[15];
    const float* hw1_w  = (const float*)d_in[6];

    unsigned short* Wt   = (unsigned short*)((char*)d_ws + WT_OFF);
    unsigned short* fc1t = (unsigned short*)((char*)d_ws + FC1T_OFF);
    float*          bq   = (float*)((char*)d_ws + BQ_OFF);

    float* out_q = (float*)d_out;                    // agents_qs [524288][5]
    float* qtot  = out_q + (size_t)ROWS_A * 5;       // q_tot [16384]

    prep_kernel<<<296, 256, 0, stream>>>(fc1_w, hw1_w, hb1_w, hwf_w, v1_w, Wt, fc1t);
    agent_kernel<<<ROWS_A / 256, 256, 0, stream>>>(obs, fc1t, fc1_b, fc2_w, fc2_b, out_q, bq);
    (void)hipFuncSetAttribute((const void*)mixer_kernel,
                              hipFuncAttributeMaxDynamicSharedMemorySize, MX_SMEM);
    mixer_kernel<<<BTOT / 64, 256, MX_SMEM, stream>>>(states, Wt, hw1_b, hb1_b, hwf_b,
                                                      v1_b, v2_w, v2_b, bq, qtot);
}